// Round 6
// baseline (614.832 us; speedup 1.0000x reference)
//
#include <hip/hip_runtime.h>

// GraphConstruction: x[1,1024,1024] fp32 -> A[4096,4096] in {0,1} fp32.
// patches[n,r,k] = x[h,w], h = (n&15)*64 + (r>>2)*16 + (n>>8),
//                          w = (r&3)*256 + k*16 + ((n>>4)&15)   (verified 6x)
// Established: typing is fp32 in / fp32 out (R4 bf16 label was harness
// boilerplate); ref is fp32 (R2 f64-truth fails); ref is NOT SSE mul+add
// (R3 fails). Round 6 candidate: numpy-with-FMA semantics:
//   sq[n,k]: temp fl(p^2), add.reduce axis=1 -> PLAIN adds, r ascending
//   G[i,j,k]: einsum sop AVX2/FMA3 -> acc = fma(a_r, b_r, acc), r ascending
//             (NpyIter: k innermost (strides 4,4,4 beat 64,64,0), r = outer
//              sequential accumulation passes)
//   d2 = fl(fl(sq_i+sq_j) - fl(2*G));  A = all_k (d2 <= 49.0f)  [== sqrt<=7]

#define NPATCH 4096
#define TILE 32

__global__ __launch_bounds__(256) void adj_kernel(const float* __restrict__ x,
                                                  float* __restrict__ A) {
#pragma clang fp contract(off)
    // Tile rows: 256 floats (layout k*16+r), float4-chunk XOR swizzle by
    // (row&15): j-side reads (16 rows @ 1 KB stride) would be 16-way bank
    // conflicts; swizzle -> conflict-free ((c^row) mod 16 distinct).
    __shared__ __align__(16) float Ai[TILE * 256];
    __shared__ __align__(16) float Aj[TILE * 256];
    __shared__ float sqi[TILE * 16];
    __shared__ float sqj[TILE * 16];

    const int i0 = blockIdx.y * TILE;
    const int j0 = blockIdx.x * TILE;
    const int tid = threadIdx.x;

    // ---- Stage both tiles directly from x (no workspace) ----
    for (int t = tid; t < TILE * 256; t += 256) {
        int row = t >> 8;
        int k = (t >> 4) & 15;
        int r = t & 15;
        int c = (k << 2) | (r >> 2);               // float4 chunk 0..63
        int pos = (row << 8) | (((c ^ (row & 15)) << 2) | (r & 3));

        int ni = i0 + row;
        int hi = (ni & 15) * 64 + (r >> 2) * 16 + (ni >> 8);
        int wi = (r & 3) * 256 + k * 16 + ((ni >> 4) & 15);
        Ai[pos] = x[hi * 1024 + wi];

        int nj = j0 + row;
        int hj = (nj & 15) * 64 + (r >> 2) * 16 + (nj >> 8);
        int wj = (r & 3) * 256 + k * 16 + ((nj >> 4) & 15);
        Aj[pos] = x[hj * 1024 + wj];
    }
    __syncthreads();

    // ---- Per-column squared norms: fl(p^2) temps, PLAIN adds, r ascending ----
    for (int s = tid; s < 2 * TILE * 16; s += 256) {
        int side = s >> 9;                          // 0: i-tile, 1: j-tile
        int idx = s & 511;
        int row = idx >> 4;
        int k = idx & 15;
        const float4* T4 = (const float4*)(side ? Aj : Ai);
        float acc = 0.0f;
        bool first = true;
#pragma unroll
        for (int rc = 0; rc < 4; ++rc) {
            int c = (k << 2) | rc;
            float4 v = T4[(row << 6) | (c ^ (row & 15))];
            if (first) { acc = v.x * v.x; first = false; }
            else       { float t0 = v.x * v.x; acc = acc + t0; }
            float t1 = v.y * v.y; acc = acc + t1;
            float t2 = v.z * v.z; acc = acc + t2;
            float t3 = v.w * v.w; acc = acc + t3;
        }
        (side ? sqj : sqi)[idx] = acc;
    }
    __syncthreads();

    // ---- 2x2 register tile, Gram: acc = fmaf(a_r, b_r, acc), r ascending ----
    const int tx = tid & 15;
    const int ty = tid >> 4;
    const int ia0 = ty, ia1 = ty + 16;
    const int ja0 = tx, ja1 = tx + 16;

    const float4* Ai4 = (const float4*)Ai;
    const float4* Aj4 = (const float4*)Aj;

    bool ok00 = true, ok01 = true, ok10 = true, ok11 = true;

    for (int k = 0; k < 16; ++k) {
        float d00 = 0.0f, d01 = 0.0f, d10 = 0.0f, d11 = 0.0f;
#pragma unroll
        for (int rc = 0; rc < 4; ++rc) {
            int c = (k << 2) | rc;
            float4 a0 = Ai4[(ia0 << 6) | (c ^ (ia0 & 15))];
            float4 a1 = Ai4[(ia1 << 6) | (c ^ (ia1 & 15))];
            float4 b0 = Aj4[(ja0 << 6) | (c ^ (ja0 & 15))];
            float4 b1 = Aj4[(ja1 << 6) | (c ^ (ja1 & 15))];
            d00 = fmaf(a0.x, b0.x, d00); d00 = fmaf(a0.y, b0.y, d00);
            d00 = fmaf(a0.z, b0.z, d00); d00 = fmaf(a0.w, b0.w, d00);
            d01 = fmaf(a0.x, b1.x, d01); d01 = fmaf(a0.y, b1.y, d01);
            d01 = fmaf(a0.z, b1.z, d01); d01 = fmaf(a0.w, b1.w, d01);
            d10 = fmaf(a1.x, b0.x, d10); d10 = fmaf(a1.y, b0.y, d10);
            d10 = fmaf(a1.z, b0.z, d10); d10 = fmaf(a1.w, b0.w, d10);
            d11 = fmaf(a1.x, b1.x, d11); d11 = fmaf(a1.y, b1.y, d11);
            d11 = fmaf(a1.z, b1.z, d11); d11 = fmaf(a1.w, b1.w, d11);
        }
        float si0 = sqi[ia0 * 16 + k];
        float si1 = sqi[ia1 * 16 + k];
        float sj0 = sqj[ja0 * 16 + k];
        float sj1 = sqj[ja1 * 16 + k];
        // d2 = fl(fl(si+sj) - fl(2*G)); contract(off) keeps sub un-fused
        float s00 = si0 + sj0, s01 = si0 + sj1;
        float s10 = si1 + sj0, s11 = si1 + sj1;
        ok00 = ok00 && ((s00 - 2.0f * d00) <= 49.0f);
        ok01 = ok01 && ((s01 - 2.0f * d01) <= 49.0f);
        ok10 = ok10 && ((s10 - 2.0f * d10) <= 49.0f);
        ok11 = ok11 && ((s11 - 2.0f * d11) <= 49.0f);
    }

    float* Arow0 = A + (size_t)(i0 + ia0) * NPATCH + j0;
    float* Arow1 = A + (size_t)(i0 + ia1) * NPATCH + j0;
    Arow0[ja0] = ok00 ? 1.0f : 0.0f;
    Arow0[ja1] = ok01 ? 1.0f : 0.0f;
    Arow1[ja0] = ok10 ? 1.0f : 0.0f;
    Arow1[ja1] = ok11 ? 1.0f : 0.0f;
}

extern "C" void kernel_launch(void* const* d_in, const int* in_sizes, int n_in,
                              void* d_out, int out_size, void* d_ws, size_t ws_size,
                              hipStream_t stream) {
    const float* x = (const float*)d_in[0];
    float* A = (float*)d_out;
    (void)d_ws; (void)ws_size;

    dim3 grid(NPATCH / TILE, NPATCH / TILE);  // 128 x 128
    adj_kernel<<<grid, 256, 0, stream>>>(x, A);
}

// Round 7
// 229.821 us; speedup vs baseline: 2.6753x; 2.6753x over previous
//
#include <hip/hip_runtime.h>

// GraphConstruction: x[1,1024,1024] fp32 -> A[4096,4096] in {0,1} fp32.
// patches[n,r,k] = x[h,w], h = (n&15)*64 + (r>>2)*16 + (n>>8),
//                          w = (r&3)*256 + k*16 + ((n>>4)&15)
// LOCKED NUMERICS (R6, passed absmax 0):
//   sq[n,k]: acc = p0^2; acc = acc + fl(p_r^2), r ascending (plain adds)
//   G: acc = fmaf(a_r, b_r, acc), r ascending
//   d2 = fl(s - 2G) via fmaf(-2,d,s)  [== ref's fl(s - fl(2G)), 2G exact]
//   decision: max_k d2 <= 49.0f
// R7: symmetry (A bit-exactly symmetric: fma args commute, fl(si+sj) symmetric)
//     -> lower-triangle blocks only + mirrored stores; 64x64 tile, 4x4/thread
//     (halves LDS reads per fma); KC=4 k-sliced staging -> 34 KB LDS
//     -> 4 blocks/CU; swizzle chunk^(row>>2) provably <=2-way on all reads.

#define NPATCH 4096
#define BT 64
#define KC 4
#define NPH 4

__global__ __launch_bounds__(256, 3) void adj_kernel(const float* __restrict__ x,
                                                     float* __restrict__ A) {
#pragma clang fp contract(off)
    // S[side][row][chunk]: chunk holds (kl,rc) at index (kl*4+rc)^(row>>2),
    // element e = r&3. Per-instr bank check: b-side rows 4tx+v -> quad =
    // (c^tx) mod 8, tx=0..15 -> 2-way (free); a-side 4 rows broadcast, clean.
    __shared__ float4 S[2][BT][16];
    __shared__ __align__(16) float sqs[2][KC][BT];

    // linear -> lower-triangle (bi >= bj)
    int t = blockIdx.x;
    int bi = (int)((sqrtf(8.0f * (float)t + 1.0f) - 1.0f) * 0.5f);
    while ((bi + 1) * (bi + 2) / 2 <= t) ++bi;
    while (bi * (bi + 1) / 2 > t) --bi;
    int bj = t - bi * (bi + 1) / 2;

    const int i0 = bi * BT;
    const int j0 = bj * BT;
    const int tid = threadIdx.x;
    const int tx = tid & 15;
    const int ty = tid >> 4;

    float m[4][4];
#pragma unroll
    for (int u = 0; u < 4; ++u)
#pragma unroll
        for (int v = 0; v < 4; ++v) m[u][v] = -3.0e38f;

    for (int kp = 0; kp < NPH; ++kp) {
        __syncthreads();  // previous phase's reads done before restage
        // ---- stage k-slice of both tiles from x ----
        for (int e0 = tid; e0 < 2 * BT * 64; e0 += 256) {
            int side = e0 >> 12;
            int q = e0 & 4095;
            int row = q >> 6;
            int f = q & 63;
            int c = f >> 2;           // kl*4+rc
            int e = f & 3;
            int kl = c >> 2;
            int rc = c & 3;
            int r = rc * 4 + e;
            int k = kp * 4 + kl;
            int n = (side ? j0 : i0) + row;
            int h = (n & 15) * 64 + (r >> 2) * 16 + (n >> 8);
            int w = (r & 3) * 256 + k * 16 + ((n >> 4) & 15);
            float val = x[h * 1024 + w];
            float* Sf = (float*)&S[side][row][0];
            Sf[((c ^ (row >> 2)) << 2) | e] = val;   // wave covers one row: conflict-free
        }
        __syncthreads();
        // ---- per-column sq for this slice: plain adds, r ascending ----
        for (int s0 = tid; s0 < 2 * BT * KC; s0 += 256) {
            int side = s0 >> 8;
            int q = s0 & 255;
            int row = q >> 2;
            int kl = q & 3;
            float acc = 0.0f;
            bool first = true;
#pragma unroll
            for (int rc = 0; rc < 4; ++rc) {
                float4 v = S[side][row][(kl * 4 + rc) ^ (row >> 2)];
                if (first) { acc = v.x * v.x; first = false; }
                else       { float t0 = v.x * v.x; acc = acc + t0; }
                float t1 = v.y * v.y; acc = acc + t1;
                float t2 = v.z * v.z; acc = acc + t2;
                float t3 = v.w * v.w; acc = acc + t3;
            }
            sqs[side][kl][row] = acc;
        }
        __syncthreads();
        // ---- compute: 4x4 cells, fmaf chains r ascending ----
#pragma unroll
        for (int kl = 0; kl < KC; ++kl) {
            float4 si = *(const float4*)&sqs[0][kl][ty * 4];
            float4 sj = *(const float4*)&sqs[1][kl][tx * 4];
            float d[4][4];
#pragma unroll
            for (int u = 0; u < 4; ++u)
#pragma unroll
                for (int v = 0; v < 4; ++v) d[u][v] = 0.0f;
#pragma unroll
            for (int rc = 0; rc < 4; ++rc) {
                int c = kl * 4 + rc;
                float4 a[4], b[4];
#pragma unroll
                for (int u = 0; u < 4; ++u) a[u] = S[0][ty * 4 + u][c ^ ty];
#pragma unroll
                for (int v = 0; v < 4; ++v) b[v] = S[1][tx * 4 + v][c ^ tx];
#pragma unroll
                for (int u = 0; u < 4; ++u)
#pragma unroll
                    for (int v = 0; v < 4; ++v) {
                        d[u][v] = fmaf(a[u].x, b[v].x, d[u][v]);
                        d[u][v] = fmaf(a[u].y, b[v].y, d[u][v]);
                        d[u][v] = fmaf(a[u].z, b[v].z, d[u][v]);
                        d[u][v] = fmaf(a[u].w, b[v].w, d[u][v]);
                    }
            }
            const float* sip = (const float*)&si;
            const float* sjp = (const float*)&sj;
#pragma unroll
            for (int u = 0; u < 4; ++u)
#pragma unroll
                for (int v = 0; v < 4; ++v) {
                    float s = sip[u] + sjp[v];          // fl(si+sj)
                    float d2 = fmaf(-2.0f, d[u][v], s); // fl(s-2G)
                    m[u][v] = fmaxf(m[u][v], d2);
                }
        }
    }

    // ---- stores: direct block + mirrored block (A exactly symmetric) ----
#pragma unroll
    for (int u = 0; u < 4; ++u) {
        float4 o;
        o.x = (m[u][0] <= 49.0f) ? 1.0f : 0.0f;
        o.y = (m[u][1] <= 49.0f) ? 1.0f : 0.0f;
        o.z = (m[u][2] <= 49.0f) ? 1.0f : 0.0f;
        o.w = (m[u][3] <= 49.0f) ? 1.0f : 0.0f;
        *(float4*)&A[(size_t)(i0 + ty * 4 + u) * NPATCH + j0 + tx * 4] = o;
    }
    if (bi != bj) {
#pragma unroll
        for (int v = 0; v < 4; ++v) {
            float4 o;
            o.x = (m[0][v] <= 49.0f) ? 1.0f : 0.0f;
            o.y = (m[1][v] <= 49.0f) ? 1.0f : 0.0f;
            o.z = (m[2][v] <= 49.0f) ? 1.0f : 0.0f;
            o.w = (m[3][v] <= 49.0f) ? 1.0f : 0.0f;
            *(float4*)&A[(size_t)(j0 + tx * 4 + v) * NPATCH + i0 + ty * 4] = o;
        }
    }
}

extern "C" void kernel_launch(void* const* d_in, const int* in_sizes, int n_in,
                              void* d_out, int out_size, void* d_ws, size_t ws_size,
                              hipStream_t stream) {
    const float* x = (const float*)d_in[0];
    float* A = (float*)d_out;
    (void)d_ws; (void)ws_size;

    const int nblk = (NPATCH / BT) * (NPATCH / BT + 1) / 2;  // 2080
    adj_kernel<<<nblk, 256, 0, stream>>>(x, A);
}